// Round 9
// baseline (81.833 us; speedup 1.0000x reference)
//
#include <hip/hip_runtime.h>
#include <hip/hip_bf16.h>
#include <math.h>

#define NP 16
#define NB 512
#define ND 2048
#define NM (NP*NB)          // 8192 rows
#define BM 128
#define BN 128
#define BK 64
#define NS (ND/BK)          // 32 K-steps

typedef __attribute__((ext_vector_type(8))) short bf16x8;
typedef __attribute__((ext_vector_type(4))) float f32x4;
typedef unsigned int u32;
typedef unsigned long long u64;

__device__ inline unsigned short f2bf(float f) {
    unsigned u = __float_as_uint(f);
    unsigned r = (u + 0x7fffu + ((u >> 16) & 1u)) >> 16;   // RNE
    return (unsigned short)r;
}

__device__ inline float dot4(float4 v) {
    return v.x * v.x + v.y * v.y + v.z * v.z + v.w * v.w;
}

// ---------------------------------------------------------------------------
// Prep: one pass over feat -> row-normalized bf16 A + normalized bf16 z row.
// 512 blocks (one per b), 512 thr = 8 waves (16 waves/CU): wave wv handles
// patches wv*2, wv*2+1.
__global__ __launch_bounds__(512) void prep_kernel(
        const float* __restrict__ feat,
        unsigned short* __restrict__ an,     // [NM][ND] bf16, row-normalized
        unsigned short* __restrict__ zn) {   // [NB][ND] bf16, row-normalized
    const int b = blockIdx.x, tid = threadIdx.x;
    const int lane = tid & 63, wv = tid >> 6;          // wv 0..7
    const float4* feat4 = (const float4*)feat;

    float4 zp[8];
#pragma unroll
    for (int it = 0; it < 8; ++it) zp[it] = make_float4(0.f, 0.f, 0.f, 0.f);

#pragma unroll
    for (int j = 0; j < 2; ++j) {
        const int p = wv * 2 + j;
        const size_t row = (size_t)p * NB + b;
        const float4* rp = feat4 + row * (ND / 4);
        float4 rv[8];
        float ss = 0.f;
#pragma unroll
        for (int it = 0; it < 8; ++it) {
            rv[it] = rp[it * 64 + lane];
            ss += dot4(rv[it]);
            zp[it].x += rv[it].x; zp[it].y += rv[it].y;
            zp[it].z += rv[it].z; zp[it].w += rv[it].w;
        }
#pragma unroll
        for (int off = 32; off > 0; off >>= 1) ss += __shfl_xor(ss, off);
        const float inv = 1.f / fmaxf(sqrtf(ss), 1e-12f);
        ushort4* wp = (ushort4*)(an + row * ND);
#pragma unroll
        for (int it = 0; it < 8; ++it) {
            ushort4 o;
            o.x = f2bf(rv[it].x * inv); o.y = f2bf(rv[it].y * inv);
            o.z = f2bf(rv[it].z * inv); o.w = f2bf(rv[it].w * inv);
            wp[it * 64 + lane] = o;
        }
    }

    __shared__ float4 zl[8][512];        // 64 KB
#pragma unroll
    for (int it = 0; it < 8; ++it) zl[wv][it * 64 + lane] = zp[it];
    __syncthreads();

    float4 z = zl[0][tid];
#pragma unroll
    for (int v = 1; v < 8; ++v) {
        float4 t = zl[v][tid];
        z.x += t.x; z.y += t.y; z.z += t.z; z.w += t.w;
    }
    float ss = dot4(z);
#pragma unroll
    for (int off = 32; off > 0; off >>= 1) ss += __shfl_xor(ss, off);
    __shared__ float wpart[8];
    __shared__ float invz_s;
    if (lane == 0) wpart[wv] = ss;
    __syncthreads();
    if (tid == 0) {
        float t = 0.f;
#pragma unroll
        for (int v = 0; v < 8; ++v) t += wpart[v];
        invz_s = 1.f / fmaxf(sqrtf(t), 1e-12f);
    }
    __syncthreads();
    const float iz = invz_s;
    ushort4 o;
    o.x = f2bf(z.x * iz); o.y = f2bf(z.y * iz);
    o.z = f2bf(z.z * iz); o.w = f2bf(z.w * iz);
    ((ushort4*)(zn + (size_t)b * ND))[tid] = o;
}

// ---------------------------------------------------------------------------
// GEMM + partial CE loss. Block = 128x128, 256 thr = 4 waves (2x2), wave tile
// 64x64 (acc[4][4]). A: global_load_lds -> 3 LDS buffers (deep fire-and-
// forget prefetch covers L3/HBM latency). B: DIRECT register loads via
// asm-volatile global_load_dwordx4 (cannot be sunk by the scheduler),
// ping-pong 2 sets, L2-hot (slice reused by 64 blocks; in-CU duplicate read
// hits L1). One barrier + one counted vmcnt(12) per step
// (12 = next step's 4 A-stage + 8 B-loads in flight).
__global__ __launch_bounds__(256, 1) void gemm_loss_kernel(
        const unsigned short* __restrict__ an, // [NM][ND] bf16
        const unsigned short* __restrict__ zn, // [NB][ND] bf16
        float* __restrict__ pmax_g,            // [4][NM]
        float* __restrict__ psum_g,            // [4][NM]
        float* __restrict__ ppos_g) {          // [NM]
    __shared__ __align__(16) unsigned char abuf[3 * BM * BK * 2];  // 3 x 16 KB
    __shared__ float sm_max[BM][2];
    __shared__ float sm_sum[BM][2];
    __shared__ float sm_pos[BM];

    const int tid  = threadIdx.x;
    const int lane = tid & 63;
    const int w    = tid >> 6;       // 0..3
    const int wr   = w >> 1;         // row strip 0..1
    const int wc   = w & 1;          // col strip 0..1
    const int l15  = lane & 15;
    const int l4   = lane >> 4;      // 0..3
    const int cb   = blockIdx.x & 3;
    const int brow = (blockIdx.x >> 2) * BM;
    const int bcol = cb * BN;

    const unsigned char* anb = (const unsigned char*)an;
    const u64 znb64 = (u64)(const unsigned char*)zn;

    // B voffsets: rows bcol + wc*64 + n*16 + l15, col chunk l4*16 bytes.
    u32 voffB[4];
#pragma unroll
    for (int n = 0; n < 4; ++n)
        voffB[n] = (u32)(bcol + wc * 64 + n * 16 + l15) * (ND * 2) + l4 * 16;

    f32x4 acc[4][4] = {};
    bf16x8 bX[2][4], bY[2][4];

#define STAGEA(BI, S) do {                                                    \
        const int koB_ = (S) * (BK * 2);                                      \
        _Pragma("unroll")                                                     \
        for (int i = 0; i < 4; ++i) {                                         \
            int q = i * 256 + tid;                                            \
            int r = q >> 3, c = q & 7;                                        \
            int cs = c ^ (r & 7);                                             \
            __builtin_amdgcn_global_load_lds(                                 \
                (const u32*)(anb + (size_t)(brow + r) * (ND * 2) + koB_ + cs * 16), \
                (u32*)(&abuf[(BI) * 16384 + q * 16]), 16, 0, 0);              \
        }                                                                     \
    } while (0)

#define LOADB(SET) do {                                                       \
        _Pragma("unroll")                                                     \
        for (int n = 0; n < 4; ++n) {                                         \
            asm volatile("global_load_dwordx4 %0, %1, %2 offset:0"            \
                : "=v"(SET[0][n]) : "v"(voffB[n]), "s"(znb64));               \
            asm volatile("global_load_dwordx4 %0, %1, %2 offset:64"           \
                : "=v"(SET[1][n]) : "v"(voffB[n]), "s"(znb64));               \
        }                                                                     \
        _Pragma("unroll")                                                     \
        for (int n = 0; n < 4; ++n) voffB[n] += BK * 2;                       \
    } while (0)

#define STEP(S, BSET, DO_STAGE, VMN) do {                                     \
        asm volatile("s_waitcnt vmcnt(" #VMN ")" ::: "memory");               \
        __builtin_amdgcn_sched_barrier(0);                                    \
        __builtin_amdgcn_s_barrier();                                         \
        __builtin_amdgcn_sched_barrier(0);                                    \
        if (DO_STAGE) STAGEA(astg, (S) + 2);                                  \
        bf16x8 af[2][4];                                                      \
        _Pragma("unroll")                                                     \
        for (int kc = 0; kc < 2; ++kc)                                        \
        _Pragma("unroll")                                                     \
        for (int m = 0; m < 4; ++m) {                                         \
            int r = wr * 64 + m * 16 + l15;                                   \
            int cs = (kc * 4 + l4) ^ (r & 7);                                 \
            af[kc][m] = *(const bf16x8*)(&abuf[acur * 16384 + r * 128 + cs * 16]); \
        }                                                                     \
        __builtin_amdgcn_s_setprio(1);                                        \
        _Pragma("unroll")                                                     \
        for (int kc = 0; kc < 2; ++kc)                                        \
        _Pragma("unroll")                                                     \
        for (int m = 0; m < 4; ++m)                                           \
        _Pragma("unroll")                                                     \
        for (int n = 0; n < 4; ++n)                                           \
            acc[m][n] = __builtin_amdgcn_mfma_f32_16x16x32_bf16(              \
                af[kc][m], BSET[kc][n], acc[m][n], 0, 0, 0);                  \
        __builtin_amdgcn_s_setprio(0);                                        \
        if (DO_STAGE) LOADB(BSET);                                            \
        asm volatile("s_waitcnt lgkmcnt(0)" ::: "memory");                    \
        __builtin_amdgcn_sched_barrier(0);                                    \
        acur = (acur == 2) ? 0 : acur + 1;                                    \
        astg = (astg == 2) ? 0 : astg + 1;                                    \
    } while (0)

    int acur = 0, astg = 2;
    STAGEA(0, 0); LOADB(bX);         // A0 stage + B0 regs
    STAGEA(1, 1); LOADB(bY);         // A1 stage + B1 regs

    for (int ss = 0; ss < NS - 2; ss += 2) {
        STEP(ss,     bX, true, 12);
        STEP(ss + 1, bY, true, 12);
    }
    STEP(NS - 2, bX, false, 12);
    STEP(NS - 1, bY, false, 0);
#undef STEP
#undef LOADB
#undef STAGEA

    // ---- epilogue: partial logsumexp over this block's 128 cols ----
#pragma unroll
    for (int m = 0; m < 4; ++m) {
#pragma unroll
        for (int r = 0; r < 4; ++r) {
            const int lrow = wr * 64 + m * 16 + l4 * 4 + r;   // local row
            float lg[4];
            float mx = -1e30f;
#pragma unroll
            for (int n = 0; n < 4; ++n) {
                lg[n] = acc[m][n][r] * 5.0f;                  // /TEMP
                mx = fmaxf(mx, lg[n]);
            }
            mx = fmaxf(mx, __shfl_xor(mx, 1));
            mx = fmaxf(mx, __shfl_xor(mx, 2));
            mx = fmaxf(mx, __shfl_xor(mx, 4));
            mx = fmaxf(mx, __shfl_xor(mx, 8));
            float se = 0.f;
#pragma unroll
            for (int n = 0; n < 4; ++n) se += __expf(lg[n] - mx);
            se += __shfl_xor(se, 1);
            se += __shfl_xor(se, 2);
            se += __shfl_xor(se, 4);
            se += __shfl_xor(se, 8);
            if (l15 == 0) { sm_max[lrow][wc] = mx; sm_sum[lrow][wc] = se; }
            const int posc = (brow + lrow) & (NB - 1);        // global row % 512
#pragma unroll
            for (int n = 0; n < 4; ++n)
                if (bcol + wc * 64 + n * 16 + l15 == posc) sm_pos[lrow] = lg[n];
        }
    }
    __syncthreads();

    if (tid < BM) {
        const int lrow = tid;
        const int grow = brow + lrow;
        const float m0 = sm_max[lrow][0], m1 = sm_max[lrow][1];
        const float gm = fmaxf(m0, m1);
        const float tot = sm_sum[lrow][0] * __expf(m0 - gm)
                        + sm_sum[lrow][1] * __expf(m1 - gm);
        pmax_g[cb * NM + grow] = gm;
        psum_g[cb * NM + grow] = tot;
        if (((grow & (NB - 1)) >> 7) == cb) ppos_g[grow] = sm_pos[lrow];
    }
}

// ---------------------------------------------------------------------------
// Combine 4 col-block partials per row -> per-row loss term -> block partial.
__global__ __launch_bounds__(256) void reduce_kernel(
        const float* __restrict__ pmax_g, const float* __restrict__ psum_g,
        const float* __restrict__ ppos_g, float* __restrict__ part) {
    const int row = blockIdx.x * 256 + threadIdx.x;   // 32 blocks x 256
    const float m0 = pmax_g[row],          m1 = pmax_g[NM + row];
    const float m2 = pmax_g[2 * NM + row], m3 = pmax_g[3 * NM + row];
    const float gm = fmaxf(fmaxf(m0, m1), fmaxf(m2, m3));
    const float tot = psum_g[row]          * __expf(m0 - gm)
                    + psum_g[NM + row]     * __expf(m1 - gm)
                    + psum_g[2 * NM + row] * __expf(m2 - gm)
                    + psum_g[3 * NM + row] * __expf(m3 - gm);
    float term = gm + __logf(tot) - ppos_g[row];
#pragma unroll
    for (int off = 32; off > 0; off >>= 1) term += __shfl_xor(term, off);
    __shared__ float wsum[4];
    const int lane = threadIdx.x & 63, wv = threadIdx.x >> 6;
    if (lane == 0) wsum[wv] = term;
    __syncthreads();
    if (threadIdx.x == 0)
        part[blockIdx.x] = wsum[0] + wsum[1] + wsum[2] + wsum[3];
}

__global__ void finalize_kernel(const float* __restrict__ part,
                                float* __restrict__ out) {
    const int lane = threadIdx.x;                       // 64 threads
    float v = (lane < 32) ? part[lane] : 0.f;
#pragma unroll
    for (int off = 32; off > 0; off >>= 1) v += __shfl_xor(v, off);
    if (lane == 0) out[0] = v * (1.0f / (float)NM);
}

extern "C" void kernel_launch(void* const* d_in, const int* in_sizes, int n_in,
                              void* d_out, int out_size, void* d_ws, size_t ws_size,
                              hipStream_t stream) {
    const float* feat = (const float*)d_in[0];

    unsigned short* an = (unsigned short*)d_ws;            // 32 MB
    unsigned short* zn = an + (size_t)NM * ND;             // 2 MB
    float* pmax = (float*)(zn + (size_t)NB * ND);          // 4*NM
    float* psum = pmax + 4 * NM;                           // 4*NM
    float* ppos = psum + 4 * NM;                           // NM
    float* part = ppos + NM;                               // 32

    prep_kernel<<<NB, 512, 0, stream>>>(feat, an, zn);
    gemm_loss_kernel<<<(NM / BM) * 4, 256, 0, stream>>>(an, zn, pmax, psum, ppos);
    reduce_kernel<<<NM / 256, 256, 0, stream>>>(pmax, psum, ppos, part);
    finalize_kernel<<<1, 64, 0, stream>>>(part, (float*)d_out);
}

// Round 10
// 68.267 us; speedup vs baseline: 1.1987x; 1.1987x over previous
//
#include <hip/hip_runtime.h>
#include <hip/hip_bf16.h>
#include <math.h>

#define NP 16
#define NB 512
#define ND 2048
#define NM (NP*NB)          // 8192 rows
#define BM 128
#define BN 64
#define BK 64
#define NS (ND/BK)          // 32 K-steps
#define NCB (NB/BN)         // 8 col-blocks

typedef __attribute__((ext_vector_type(8))) short bf16x8;
typedef __attribute__((ext_vector_type(4))) float f32x4;
typedef unsigned int u32;

__device__ inline unsigned short f2bf(float f) {
    unsigned u = __float_as_uint(f);
    unsigned r = (u + 0x7fffu + ((u >> 16) & 1u)) >> 16;   // RNE
    return (unsigned short)r;
}

__device__ inline float dot4(float4 v) {
    return v.x * v.x + v.y * v.y + v.z * v.z + v.w * v.w;
}

// ---------------------------------------------------------------------------
// Prep: one pass over feat -> row-normalized bf16 A + normalized bf16 z row.
__global__ __launch_bounds__(512) void prep_kernel(
        const float* __restrict__ feat,
        unsigned short* __restrict__ an,     // [NM][ND] bf16, row-normalized
        unsigned short* __restrict__ zn) {   // [NB][ND] bf16, row-normalized
    const int b = blockIdx.x, tid = threadIdx.x;
    const int lane = tid & 63, wv = tid >> 6;          // wv 0..7
    const float4* feat4 = (const float4*)feat;

    float4 zp[8];
#pragma unroll
    for (int it = 0; it < 8; ++it) zp[it] = make_float4(0.f, 0.f, 0.f, 0.f);

#pragma unroll
    for (int j = 0; j < 2; ++j) {
        const int p = wv * 2 + j;
        const size_t row = (size_t)p * NB + b;
        const float4* rp = feat4 + row * (ND / 4);
        float4 rv[8];
        float ss = 0.f;
#pragma unroll
        for (int it = 0; it < 8; ++it) {
            rv[it] = rp[it * 64 + lane];
            ss += dot4(rv[it]);
            zp[it].x += rv[it].x; zp[it].y += rv[it].y;
            zp[it].z += rv[it].z; zp[it].w += rv[it].w;
        }
#pragma unroll
        for (int off = 32; off > 0; off >>= 1) ss += __shfl_xor(ss, off);
        const float inv = 1.f / fmaxf(sqrtf(ss), 1e-12f);
        ushort4* wp = (ushort4*)(an + row * ND);
#pragma unroll
        for (int it = 0; it < 8; ++it) {
            ushort4 o;
            o.x = f2bf(rv[it].x * inv); o.y = f2bf(rv[it].y * inv);
            o.z = f2bf(rv[it].z * inv); o.w = f2bf(rv[it].w * inv);
            wp[it * 64 + lane] = o;
        }
    }

    __shared__ float4 zl[8][512];        // 64 KB
#pragma unroll
    for (int it = 0; it < 8; ++it) zl[wv][it * 64 + lane] = zp[it];
    __syncthreads();

    float4 z = zl[0][tid];
#pragma unroll
    for (int v = 1; v < 8; ++v) {
        float4 t = zl[v][tid];
        z.x += t.x; z.y += t.y; z.z += t.z; z.w += t.w;
    }
    float ss = dot4(z);
#pragma unroll
    for (int off = 32; off > 0; off >>= 1) ss += __shfl_xor(ss, off);
    __shared__ float wpart[8];
    __shared__ float invz_s;
    if (lane == 0) wpart[wv] = ss;
    __syncthreads();
    if (tid == 0) {
        float t = 0.f;
#pragma unroll
        for (int v = 0; v < 8; ++v) t += wpart[v];
        invz_s = 1.f / fmaxf(sqrtf(t), 1e-12f);
    }
    __syncthreads();
    const float iz = invz_s;
    ushort4 o;
    o.x = f2bf(z.x * iz); o.y = f2bf(z.y * iz);
    o.z = f2bf(z.z * iz); o.w = f2bf(z.w * iz);
    ((ushort4*)(zn + (size_t)b * ND))[tid] = o;
}

// ---------------------------------------------------------------------------
// GEMM + partial CE loss. Block = 128x64, 256 thr = 4 waves (2x2), wave tile
// 64x32 (acc[4][2]). Grid 512 -> 2 blocks/CU co-resident (cross-block overlap
// hides barrier/wait bubbles; __launch_bounds__(256,2), LDS 74 KB/block).
// A and B both via global_load_lds into 3 LDS buffers, single barrier +
// single counted vmcnt(6) per step (6 loads/thread/stage, wave-uniform).
// Swizzle cs = c ^ (r&7) on global source + LDS read (linear LDS dest).
__global__ __launch_bounds__(256, 2) void gemm_loss_kernel(
        const unsigned short* __restrict__ an, // [NM][ND] bf16
        const unsigned short* __restrict__ zn, // [NB][ND] bf16
        float* __restrict__ pmax_g,            // [NCB][NM]
        float* __restrict__ psum_g,            // [NCB][NM]
        float* __restrict__ ppos_g) {          // [NM]
    __shared__ __align__(16) unsigned char abuf[3 * BM * BK * 2];  // 3 x 16 KB
    __shared__ __align__(16) unsigned char bbuf[3 * BN * BK * 2];  // 3 x 8 KB
    __shared__ float sm_max[BM][2];
    __shared__ float sm_sum[BM][2];
    __shared__ float sm_pos[BM];

    const int tid  = threadIdx.x;
    const int lane = tid & 63;
    const int w    = tid >> 6;       // 0..3
    const int wr   = w >> 1;         // row strip 0..1 (64 rows each)
    const int wc   = w & 1;          // col strip 0..1 (32 cols each)
    const int l15  = lane & 15;
    const int l4   = lane >> 4;      // 0..3
    const int cb   = blockIdx.x & (NCB - 1);
    const int brow = (blockIdx.x >> 3) * BM;
    const int bcol = cb * BN;

    const unsigned char* anb = (const unsigned char*)an;
    const unsigned char* znb = (const unsigned char*)zn;

    f32x4 acc[4][2] = {};

#define STAGE(BI, S) do {                                                     \
        const int koB_ = (S) * (BK * 2);                                      \
        _Pragma("unroll")                                                     \
        for (int i = 0; i < 4; ++i) {      /* A: 128 rows x 8 chunks */       \
            int q = i * 256 + tid;                                            \
            int r = q >> 3, c = q & 7;                                        \
            int cs = c ^ (r & 7);                                             \
            __builtin_amdgcn_global_load_lds(                                 \
                (const u32*)(anb + (size_t)(brow + r) * (ND * 2) + koB_ + cs * 16), \
                (u32*)(&abuf[(BI) * 16384 + q * 16]), 16, 0, 0);              \
        }                                                                     \
        _Pragma("unroll")                                                     \
        for (int i = 0; i < 2; ++i) {      /* B: 64 rows x 8 chunks */        \
            int q = i * 256 + tid;                                            \
            int r = q >> 3, c = q & 7;                                        \
            int cs = c ^ (r & 7);                                             \
            __builtin_amdgcn_global_load_lds(                                 \
                (const u32*)(znb + (size_t)(bcol + r) * (ND * 2) + koB_ + cs * 16), \
                (u32*)(&bbuf[(BI) * 8192 + q * 16]), 16, 0, 0);               \
        }                                                                     \
    } while (0)

    STAGE(0, 0);
    STAGE(1, 1);

    int acur = 0, astg = 2;
    for (int s = 0; s < NS; ++s) {
        if (s + 1 < NS) asm volatile("s_waitcnt vmcnt(6)" ::: "memory");
        else            asm volatile("s_waitcnt vmcnt(0)" ::: "memory");
        __builtin_amdgcn_sched_barrier(0);
        __builtin_amdgcn_s_barrier();          // buf staged by ALL waves;
        __builtin_amdgcn_sched_barrier(0);     // prev-step reads all retired

        bf16x8 af[2][4], bf[2][2];
#pragma unroll
        for (int kc = 0; kc < 2; ++kc) {
#pragma unroll
            for (int m = 0; m < 4; ++m) {
                int r = wr * 64 + m * 16 + l15;
                int cs = (kc * 4 + l4) ^ (r & 7);
                af[kc][m] = *(const bf16x8*)(&abuf[acur * 16384 + r * 128 + cs * 16]);
            }
#pragma unroll
            for (int n = 0; n < 2; ++n) {
                int r = wc * 32 + n * 16 + l15;
                int cs = (kc * 4 + l4) ^ (r & 7);
                bf[kc][n] = *(const bf16x8*)(&bbuf[acur * 8192 + r * 128 + cs * 16]);
            }
        }

        if (s + 2 < NS) STAGE(astg, s + 2);    // DMA flies under the MFMAs

        __builtin_amdgcn_s_setprio(1);
#pragma unroll
        for (int kc = 0; kc < 2; ++kc)
#pragma unroll
        for (int m = 0; m < 4; ++m)
#pragma unroll
        for (int n = 0; n < 2; ++n)
            acc[m][n] = __builtin_amdgcn_mfma_f32_16x16x32_bf16(
                af[kc][m], bf[kc][n], acc[m][n], 0, 0, 0);
        __builtin_amdgcn_s_setprio(0);

        acur = (acur == 2) ? 0 : acur + 1;
        astg = (astg == 2) ? 0 : astg + 1;
    }
#undef STAGE

    // ---- epilogue: partial logsumexp over this block's 64 cols ----
#pragma unroll
    for (int m = 0; m < 4; ++m) {
#pragma unroll
        for (int r = 0; r < 4; ++r) {
            const int lrow = wr * 64 + m * 16 + l4 * 4 + r;   // local row
            float lg[2];
            float mx = -1e30f;
#pragma unroll
            for (int n = 0; n < 2; ++n) {
                lg[n] = acc[m][n][r] * 5.0f;                  // /TEMP
                mx = fmaxf(mx, lg[n]);
            }
            mx = fmaxf(mx, __shfl_xor(mx, 1));
            mx = fmaxf(mx, __shfl_xor(mx, 2));
            mx = fmaxf(mx, __shfl_xor(mx, 4));
            mx = fmaxf(mx, __shfl_xor(mx, 8));
            float se = 0.f;
#pragma unroll
            for (int n = 0; n < 2; ++n) se += __expf(lg[n] - mx);
            se += __shfl_xor(se, 1);
            se += __shfl_xor(se, 2);
            se += __shfl_xor(se, 4);
            se += __shfl_xor(se, 8);
            if (l15 == 0) { sm_max[lrow][wc] = mx; sm_sum[lrow][wc] = se; }
            const int posc = (brow + lrow) & (NB - 1);        // global row % 512
#pragma unroll
            for (int n = 0; n < 2; ++n)
                if (bcol + wc * 32 + n * 16 + l15 == posc) sm_pos[lrow] = lg[n];
        }
    }
    __syncthreads();

    if (tid < BM) {
        const int lrow = tid;
        const int grow = brow + lrow;
        const float m0 = sm_max[lrow][0], m1 = sm_max[lrow][1];
        const float gm = fmaxf(m0, m1);
        const float tot = sm_sum[lrow][0] * __expf(m0 - gm)
                        + sm_sum[lrow][1] * __expf(m1 - gm);
        pmax_g[cb * NM + grow] = gm;
        psum_g[cb * NM + grow] = tot;
        if (((grow & (NB - 1)) >> 6) == cb) ppos_g[grow] = sm_pos[lrow];
    }
}

// ---------------------------------------------------------------------------
// Combine 8 col-block partials per row -> per-row loss term -> block partial.
__global__ __launch_bounds__(256) void reduce_kernel(
        const float* __restrict__ pmax_g, const float* __restrict__ psum_g,
        const float* __restrict__ ppos_g, float* __restrict__ part) {
    const int row = blockIdx.x * 256 + threadIdx.x;   // 32 blocks x 256
    float mxs[NCB];
    float gm = -1e30f;
#pragma unroll
    for (int c = 0; c < NCB; ++c) {
        mxs[c] = pmax_g[c * NM + row];
        gm = fmaxf(gm, mxs[c]);
    }
    float tot = 0.f;
#pragma unroll
    for (int c = 0; c < NCB; ++c)
        tot += psum_g[c * NM + row] * __expf(mxs[c] - gm);
    float term = gm + __logf(tot) - ppos_g[row];
#pragma unroll
    for (int off = 32; off > 0; off >>= 1) term += __shfl_xor(term, off);
    __shared__ float wsum[4];
    const int lane = threadIdx.x & 63, wv = threadIdx.x >> 6;
    if (lane == 0) wsum[wv] = term;
    __syncthreads();
    if (threadIdx.x == 0)
        part[blockIdx.x] = wsum[0] + wsum[1] + wsum[2] + wsum[3];
}

__global__ void finalize_kernel(const float* __restrict__ part,
                                float* __restrict__ out) {
    const int lane = threadIdx.x;                       // 64 threads
    float v = (lane < 32) ? part[lane] : 0.f;
#pragma unroll
    for (int off = 32; off > 0; off >>= 1) v += __shfl_xor(v, off);
    if (lane == 0) out[0] = v * (1.0f / (float)NM);
}

extern "C" void kernel_launch(void* const* d_in, const int* in_sizes, int n_in,
                              void* d_out, int out_size, void* d_ws, size_t ws_size,
                              hipStream_t stream) {
    const float* feat = (const float*)d_in[0];

    unsigned short* an = (unsigned short*)d_ws;            // 32 MB
    unsigned short* zn = an + (size_t)NM * ND;             // 2 MB
    float* pmax = (float*)(zn + (size_t)NB * ND);          // NCB*NM
    float* psum = pmax + NCB * NM;                         // NCB*NM
    float* ppos = psum + NCB * NM;                         // NM
    float* part = ppos + NM;                               // 32

    prep_kernel<<<NB, 512, 0, stream>>>(feat, an, zn);
    gemm_loss_kernel<<<(NM / BM) * NCB, 256, 0, stream>>>(an, zn, pmax, psum, ppos);
    reduce_kernel<<<NM / 256, 256, 0, stream>>>(pmax, psum, ppos, part);
    finalize_kernel<<<1, 64, 0, stream>>>(part, (float*)d_out);
}

// Round 11
// 52.447 us; speedup vs baseline: 1.5603x; 1.3016x over previous
//
#include <hip/hip_runtime.h>
#include <hip/hip_bf16.h>
#include <math.h>

#define NP 16
#define NB 512
#define ND 2048
#define NM (NP*NB)          // 8192 rows
#define BM 128
#define BN 128
#define BK 64
#define NS (ND/BK)          // 32 K-steps
#define NCB (NB/BN)         // 4 col-blocks

typedef __attribute__((ext_vector_type(8))) short bf16x8;
typedef __attribute__((ext_vector_type(4))) float f32x4;
typedef unsigned int u32;

__device__ inline unsigned short f2bf(float f) {
    unsigned u = __float_as_uint(f);
    unsigned r = (u + 0x7fffu + ((u >> 16) & 1u)) >> 16;   // RNE
    return (unsigned short)r;
}

__device__ inline float dot4(float4 v) {
    return v.x * v.x + v.y * v.y + v.z * v.z + v.w * v.w;
}

// ---------------------------------------------------------------------------
// Prep: one pass over feat -> row-normalized bf16 A + normalized bf16 z row.
__global__ __launch_bounds__(512) void prep_kernel(
        const float* __restrict__ feat,
        unsigned short* __restrict__ an,     // [NM][ND] bf16, row-normalized
        unsigned short* __restrict__ zn) {   // [NB][ND] bf16, row-normalized
    const int b = blockIdx.x, tid = threadIdx.x;
    const int lane = tid & 63, wv = tid >> 6;          // wv 0..7
    const float4* feat4 = (const float4*)feat;

    float4 zp[8];
#pragma unroll
    for (int it = 0; it < 8; ++it) zp[it] = make_float4(0.f, 0.f, 0.f, 0.f);

#pragma unroll
    for (int j = 0; j < 2; ++j) {
        const int p = wv * 2 + j;
        const size_t row = (size_t)p * NB + b;
        const float4* rp = feat4 + row * (ND / 4);
        float4 rv[8];
        float ss = 0.f;
#pragma unroll
        for (int it = 0; it < 8; ++it) {
            rv[it] = rp[it * 64 + lane];
            ss += dot4(rv[it]);
            zp[it].x += rv[it].x; zp[it].y += rv[it].y;
            zp[it].z += rv[it].z; zp[it].w += rv[it].w;
        }
#pragma unroll
        for (int off = 32; off > 0; off >>= 1) ss += __shfl_xor(ss, off);
        const float inv = 1.f / fmaxf(sqrtf(ss), 1e-12f);
        ushort4* wp = (ushort4*)(an + row * ND);
#pragma unroll
        for (int it = 0; it < 8; ++it) {
            ushort4 o;
            o.x = f2bf(rv[it].x * inv); o.y = f2bf(rv[it].y * inv);
            o.z = f2bf(rv[it].z * inv); o.w = f2bf(rv[it].w * inv);
            wp[it * 64 + lane] = o;
        }
    }

    __shared__ float4 zl[8][512];        // 64 KB
#pragma unroll
    for (int it = 0; it < 8; ++it) zl[wv][it * 64 + lane] = zp[it];
    __syncthreads();

    float4 z = zl[0][tid];
#pragma unroll
    for (int v = 1; v < 8; ++v) {
        float4 t = zl[v][tid];
        z.x += t.x; z.y += t.y; z.z += t.z; z.w += t.w;
    }
    float ss = dot4(z);
#pragma unroll
    for (int off = 32; off > 0; off >>= 1) ss += __shfl_xor(ss, off);
    __shared__ float wpart[8];
    __shared__ float invz_s;
    if (lane == 0) wpart[wv] = ss;
    __syncthreads();
    if (tid == 0) {
        float t = 0.f;
#pragma unroll
        for (int v = 0; v < 8; ++v) t += wpart[v];
        invz_s = 1.f / fmaxf(sqrtf(t), 1e-12f);
    }
    __syncthreads();
    const float iz = invz_s;
    ushort4 o;
    o.x = f2bf(z.x * iz); o.y = f2bf(z.y * iz);
    o.z = f2bf(z.z * iz); o.w = f2bf(z.w * iz);
    ((ushort4*)(zn + (size_t)b * ND))[tid] = o;
}

// ---------------------------------------------------------------------------
// GEMM + partial CE loss. Block = 128x128, 512 thr = 8 waves (2 wr x 4 wc),
// wave tile 64x32 (acc[4][2]) -> 2 waves/SIMD so MFMA/ds_read/wait bubbles of
// one wave are filled by the other. Grid 256 = 1 block/CU, NCB=4 keeps A
// fabric traffic ~1x (R8-verified: FETCH ~= A size; each XCD sees one fixed
// zn slice since bid&3 is constant per XCD). 3 LDS buffers, 2-deep
// global_load_lds staging (4 loads/thread/stage -> uniform vmcnt(4)), ONE
// barrier per step. Overwrite safety: reads of step s-1 are consumed by that
// step's MFMAs (lgkmcnt) before any wave passes barrier s and stages s+2.
// Swizzle cs = c ^ (r&7) on global source + LDS read (linear LDS dest).
__global__ __launch_bounds__(512, 1) void gemm_loss_kernel(
        const unsigned short* __restrict__ an, // [NM][ND] bf16
        const unsigned short* __restrict__ zn, // [NB][ND] bf16
        float* __restrict__ pmax_g,            // [NCB][NM]
        float* __restrict__ psum_g,            // [NCB][NM]
        float* __restrict__ ppos_g) {          // [NM]
    __shared__ __align__(16) unsigned char abuf[3 * BM * BK * 2];  // 3 x 16 KB
    __shared__ __align__(16) unsigned char bbuf[3 * BN * BK * 2];  // 3 x 16 KB
    __shared__ float sm_max[BM][4];
    __shared__ float sm_sum[BM][4];
    __shared__ float sm_pos[BM];

    const int tid  = threadIdx.x;
    const int lane = tid & 63;
    const int w    = tid >> 6;       // 0..7
    const int wr   = w >> 2;         // row strip 0..1 (64 rows each)
    const int wc   = w & 3;          // col strip 0..3 (32 cols each)
    const int l15  = lane & 15;
    const int l4   = lane >> 4;      // 0..3
    const int cb   = blockIdx.x & (NCB - 1);
    const int brow = (blockIdx.x >> 2) * BM;
    const int bcol = cb * BN;

    const unsigned char* anb = (const unsigned char*)an;
    const unsigned char* znb = (const unsigned char*)zn;

    f32x4 acc[4][2] = {};

#define STAGE(BI, S) do {                                                     \
        const int koB_ = (S) * (BK * 2);                                      \
        _Pragma("unroll")                                                     \
        for (int i = 0; i < 2; ++i) {      /* A: 128 rows x 8 chunks */       \
            int q = i * 512 + tid;                                            \
            int r = q >> 3, c = q & 7;                                        \
            int cs = c ^ (r & 7);                                             \
            __builtin_amdgcn_global_load_lds(                                 \
                (const u32*)(anb + (size_t)(brow + r) * (ND * 2) + koB_ + cs * 16), \
                (u32*)(&abuf[(BI) * 16384 + q * 16]), 16, 0, 0);              \
        }                                                                     \
        _Pragma("unroll")                                                     \
        for (int i = 0; i < 2; ++i) {      /* B: 128 rows x 8 chunks */       \
            int q = i * 512 + tid;                                            \
            int r = q >> 3, c = q & 7;                                        \
            int cs = c ^ (r & 7);                                             \
            __builtin_amdgcn_global_load_lds(                                 \
                (const u32*)(znb + (size_t)(bcol + r) * (ND * 2) + koB_ + cs * 16), \
                (u32*)(&bbuf[(BI) * 16384 + q * 16]), 16, 0, 0);              \
        }                                                                     \
    } while (0)

    STAGE(0, 0);
    STAGE(1, 1);

    int acur = 0, astg = 2;
    for (int s = 0; s < NS; ++s) {
        if (s + 1 < NS) asm volatile("s_waitcnt vmcnt(4)" ::: "memory");
        else            asm volatile("s_waitcnt vmcnt(0)" ::: "memory");
        __builtin_amdgcn_sched_barrier(0);
        __builtin_amdgcn_s_barrier();          // buf staged by ALL waves;
        __builtin_amdgcn_sched_barrier(0);     // prev-step reads all retired

        bf16x8 af[2][4], bf[2][2];
#pragma unroll
        for (int kc = 0; kc < 2; ++kc) {
#pragma unroll
            for (int m = 0; m < 4; ++m) {
                int r = wr * 64 + m * 16 + l15;
                int cs = (kc * 4 + l4) ^ (r & 7);
                af[kc][m] = *(const bf16x8*)(&abuf[acur * 16384 + r * 128 + cs * 16]);
            }
#pragma unroll
            for (int n = 0; n < 2; ++n) {
                int r = wc * 32 + n * 16 + l15;
                int cs = (kc * 4 + l4) ^ (r & 7);
                bf[kc][n] = *(const bf16x8*)(&bbuf[acur * 16384 + r * 128 + cs * 16]);
            }
        }

        if (s + 2 < NS) STAGE(astg, s + 2);    // DMA flies under the MFMAs

        __builtin_amdgcn_s_setprio(1);
#pragma unroll
        for (int kc = 0; kc < 2; ++kc)
#pragma unroll
        for (int m = 0; m < 4; ++m)
#pragma unroll
        for (int n = 0; n < 2; ++n)
            acc[m][n] = __builtin_amdgcn_mfma_f32_16x16x32_bf16(
                af[kc][m], bf[kc][n], acc[m][n], 0, 0, 0);
        __builtin_amdgcn_s_setprio(0);

        acur = (acur == 2) ? 0 : acur + 1;
        astg = (astg == 2) ? 0 : astg + 1;
    }
#undef STAGE

    // ---- epilogue: partial logsumexp over this block's 128 cols ----
#pragma unroll
    for (int m = 0; m < 4; ++m) {
#pragma unroll
        for (int r = 0; r < 4; ++r) {
            const int lrow = wr * 64 + m * 16 + l4 * 4 + r;   // local row
            float lg[2];
            float mx = -1e30f;
#pragma unroll
            for (int n = 0; n < 2; ++n) {
                lg[n] = acc[m][n][r] * 5.0f;                  // /TEMP
                mx = fmaxf(mx, lg[n]);
            }
            mx = fmaxf(mx, __shfl_xor(mx, 1));
            mx = fmaxf(mx, __shfl_xor(mx, 2));
            mx = fmaxf(mx, __shfl_xor(mx, 4));
            mx = fmaxf(mx, __shfl_xor(mx, 8));
            float se = 0.f;
#pragma unroll
            for (int n = 0; n < 2; ++n) se += __expf(lg[n] - mx);
            se += __shfl_xor(se, 1);
            se += __shfl_xor(se, 2);
            se += __shfl_xor(se, 4);
            se += __shfl_xor(se, 8);
            if (l15 == 0) { sm_max[lrow][wc] = mx; sm_sum[lrow][wc] = se; }
            const int posc = (brow + lrow) & (NB - 1);        // global row % 512
#pragma unroll
            for (int n = 0; n < 2; ++n)
                if (bcol + wc * 32 + n * 16 + l15 == posc) sm_pos[lrow] = lg[n];
        }
    }
    __syncthreads();

    if (tid < BM) {
        const int lrow = tid;
        const int grow = brow + lrow;
        float gm = -1e30f;
#pragma unroll
        for (int c = 0; c < 4; ++c) gm = fmaxf(gm, sm_max[lrow][c]);
        float tot = 0.f;
#pragma unroll
        for (int c = 0; c < 4; ++c)
            tot += sm_sum[lrow][c] * __expf(sm_max[lrow][c] - gm);
        pmax_g[cb * NM + grow] = gm;
        psum_g[cb * NM + grow] = tot;
        if (((grow & (NB - 1)) >> 7) == cb) ppos_g[grow] = sm_pos[lrow];
    }
}

// ---------------------------------------------------------------------------
// Combine 4 col-block partials per row -> per-row loss term -> block partial.
__global__ __launch_bounds__(256) void reduce_kernel(
        const float* __restrict__ pmax_g, const float* __restrict__ psum_g,
        const float* __restrict__ ppos_g, float* __restrict__ part) {
    const int row = blockIdx.x * 256 + threadIdx.x;   // 32 blocks x 256
    float mxs[NCB];
    float gm = -1e30f;
#pragma unroll
    for (int c = 0; c < NCB; ++c) {
        mxs[c] = pmax_g[c * NM + row];
        gm = fmaxf(gm, mxs[c]);
    }
    float tot = 0.f;
#pragma unroll
    for (int c = 0; c < NCB; ++c)
        tot += psum_g[c * NM + row] * __expf(mxs[c] - gm);
    float term = gm + __logf(tot) - ppos_g[row];
#pragma unroll
    for (int off = 32; off > 0; off >>= 1) term += __shfl_xor(term, off);
    __shared__ float wsum[4];
    const int lane = threadIdx.x & 63, wv = threadIdx.x >> 6;
    if (lane == 0) wsum[wv] = term;
    __syncthreads();
    if (threadIdx.x == 0)
        part[blockIdx.x] = wsum[0] + wsum[1] + wsum[2] + wsum[3];
}

__global__ void finalize_kernel(const float* __restrict__ part,
                                float* __restrict__ out) {
    const int lane = threadIdx.x;                       // 64 threads
    float v = (lane < 32) ? part[lane] : 0.f;
#pragma unroll
    for (int off = 32; off > 0; off >>= 1) v += __shfl_xor(v, off);
    if (lane == 0) out[0] = v * (1.0f / (float)NM);
}

extern "C" void kernel_launch(void* const* d_in, const int* in_sizes, int n_in,
                              void* d_out, int out_size, void* d_ws, size_t ws_size,
                              hipStream_t stream) {
    const float* feat = (const float*)d_in[0];

    unsigned short* an = (unsigned short*)d_ws;            // 32 MB
    unsigned short* zn = an + (size_t)NM * ND;             // 2 MB
    float* pmax = (float*)(zn + (size_t)NB * ND);          // NCB*NM
    float* psum = pmax + NCB * NM;                         // NCB*NM
    float* ppos = psum + NCB * NM;                         // NM
    float* part = ppos + NM;                               // 32

    prep_kernel<<<NB, 512, 0, stream>>>(feat, an, zn);
    gemm_loss_kernel<<<(NM / BM) * NCB, 512, 0, stream>>>(an, zn, pmax, psum, ppos);
    reduce_kernel<<<NM / 256, 256, 0, stream>>>(pmax, psum, ppos, part);
    finalize_kernel<<<1, 64, 0, stream>>>(part, (float*)d_out);
}

// Round 12
// 47.832 us; speedup vs baseline: 1.7109x; 1.0965x over previous
//
#include <hip/hip_runtime.h>
#include <hip/hip_bf16.h>
#include <math.h>

#define NP 16
#define NB 512
#define ND 2048
#define NM (NP*NB)          // 8192 rows
#define BM 128
#define BN 128
#define BK 64               // 64 k-elems = 64 bytes per row per step (fp8)
#define NS (ND/BK)          // 32 K-steps
#define NCB (NB/BN)         // 4 col-blocks

typedef __attribute__((ext_vector_type(4))) float f32x4;
typedef unsigned int u32;

__device__ inline float dot4(float4 v) {
    return v.x * v.x + v.y * v.y + v.z * v.z + v.w * v.w;
}

// ---- f32x4 -> 4 packed OCP e4m3fn bytes (HW cvt; RNE, saturating) --------
#if __has_builtin(__builtin_amdgcn_cvt_pk_fp8_f32)
__device__ inline u32 pack4_fp8(float a, float b, float c, float d) {
    int w = 0;
    w = __builtin_amdgcn_cvt_pk_fp8_f32(a, b, w, false);  // bytes 0,1
    w = __builtin_amdgcn_cvt_pk_fp8_f32(c, d, w, true);   // bytes 2,3
    return (u32)w;
}
#else
#include <hip/hip_fp8.h>
__device__ inline u32 pack4_fp8(float a, float b, float c, float d) {
    u32 w  = (u32)__hip_cvt_float_to_fp8(a, __HIP_SATFINITE, __HIP_E4M3);
    w |= (u32)__hip_cvt_float_to_fp8(b, __HIP_SATFINITE, __HIP_E4M3) << 8;
    w |= (u32)__hip_cvt_float_to_fp8(c, __HIP_SATFINITE, __HIP_E4M3) << 16;
    w |= (u32)__hip_cvt_float_to_fp8(d, __HIP_SATFINITE, __HIP_E4M3) << 24;
    return w;
}
#endif

// ---------------------------------------------------------------------------
// Prep: one pass over feat -> row-normalized fp8 A + normalized fp8 z row.
__global__ __launch_bounds__(512) void prep_kernel(
        const float* __restrict__ feat,
        unsigned char* __restrict__ an,      // [NM][ND] fp8, row-normalized
        unsigned char* __restrict__ zn) {    // [NB][ND] fp8, row-normalized
    const int b = blockIdx.x, tid = threadIdx.x;
    const int lane = tid & 63, wv = tid >> 6;          // wv 0..7
    const float4* feat4 = (const float4*)feat;

    float4 zp[8];
#pragma unroll
    for (int it = 0; it < 8; ++it) zp[it] = make_float4(0.f, 0.f, 0.f, 0.f);

#pragma unroll
    for (int j = 0; j < 2; ++j) {
        const int p = wv * 2 + j;
        const size_t row = (size_t)p * NB + b;
        const float4* rp = feat4 + row * (ND / 4);
        float4 rv[8];
        float ss = 0.f;
#pragma unroll
        for (int it = 0; it < 8; ++it) {
            rv[it] = rp[it * 64 + lane];
            ss += dot4(rv[it]);
            zp[it].x += rv[it].x; zp[it].y += rv[it].y;
            zp[it].z += rv[it].z; zp[it].w += rv[it].w;
        }
#pragma unroll
        for (int off = 32; off > 0; off >>= 1) ss += __shfl_xor(ss, off);
        const float inv = 1.f / fmaxf(sqrtf(ss), 1e-12f);
        u32* wp = (u32*)(an + row * ND);
#pragma unroll
        for (int it = 0; it < 8; ++it)
            wp[it * 64 + lane] = pack4_fp8(rv[it].x * inv, rv[it].y * inv,
                                           rv[it].z * inv, rv[it].w * inv);
    }

    __shared__ float4 zl[8][512];        // 64 KB
#pragma unroll
    for (int it = 0; it < 8; ++it) zl[wv][it * 64 + lane] = zp[it];
    __syncthreads();

    float4 z = zl[0][tid];
#pragma unroll
    for (int v = 1; v < 8; ++v) {
        float4 t = zl[v][tid];
        z.x += t.x; z.y += t.y; z.z += t.z; z.w += t.w;
    }
    float ss = dot4(z);
#pragma unroll
    for (int off = 32; off > 0; off >>= 1) ss += __shfl_xor(ss, off);
    __shared__ float wpart[8];
    __shared__ float invz_s;
    if (lane == 0) wpart[wv] = ss;
    __syncthreads();
    if (tid == 0) {
        float t = 0.f;
#pragma unroll
        for (int v = 0; v < 8; ++v) t += wpart[v];
        invz_s = 1.f / fmaxf(sqrtf(t), 1e-12f);
    }
    __syncthreads();
    const float iz = invz_s;
    ((u32*)(zn + (size_t)b * ND))[tid] =
        pack4_fp8(z.x * iz, z.y * iz, z.z * iz, z.w * iz);
}

// ---------------------------------------------------------------------------
// GEMM + partial CE loss, fp8 e4m3 operands. Block = 128x128, 512 thr =
// 8 waves (2x4), wave tile 64x32 (acc[4][2]); mfma_f32_16x16x32_fp8_fp8
// (same shape/rate as bf16, half the bytes). 3 LDS buffers (3 x 16 KB total),
// 2-deep global_load_lds staging (2 loads/thread/stage -> vmcnt(2)), ONE
// barrier per step. Swizzle involution c ^= (r>>2)&3 on 16B granules, applied
// to BOTH the global source and the ds_read addresses (linear LDS dest).
__global__ __launch_bounds__(512, 1) void gemm_loss_kernel(
        const unsigned char* __restrict__ an, // [NM][ND] fp8
        const unsigned char* __restrict__ zn, // [NB][ND] fp8
        float* __restrict__ pmax_g,           // [NCB][NM]
        float* __restrict__ psum_g,           // [NCB][NM]
        float* __restrict__ ppos_g) {         // [NM]
    __shared__ __align__(16) unsigned char abuf[3 * BM * BK];  // 3 x 8 KB
    __shared__ __align__(16) unsigned char bbuf[3 * BN * BK];  // 3 x 8 KB
    __shared__ float sm_max[BM][4];
    __shared__ float sm_sum[BM][4];
    __shared__ float sm_pos[BM];

    const int tid  = threadIdx.x;
    const int lane = tid & 63;
    const int w    = tid >> 6;       // 0..7
    const int wr   = w >> 2;         // row strip 0..1 (64 rows each)
    const int wc   = w & 3;          // col strip 0..3 (32 cols each)
    const int l15  = lane & 15;
    const int l4   = lane >> 4;      // 0..3
    const int cb   = blockIdx.x & (NCB - 1);
    const int brow = (blockIdx.x >> 2) * BM;
    const int bcol = cb * BN;

    f32x4 acc[4][2] = {};

    // stage: 128 rows x 64 B = 512 x 16B chunks; tid -> 1 chunk each of A, B
    const int sr  = tid >> 2;                       // row 0..127
    const int scs = (tid & 3) ^ ((sr >> 2) & 3);    // swizzled 16B granule
    const unsigned char* asrc = an + (size_t)(brow + sr) * ND + scs * 16;
    const unsigned char* bsrc = zn + (size_t)(bcol + sr) * ND + scs * 16;

#define STAGE(BI, S) do {                                                     \
        const int koB_ = (S) * BK;                                            \
        __builtin_amdgcn_global_load_lds((const u32*)(asrc + koB_),           \
            (u32*)(&abuf[(BI) * 8192 + tid * 16]), 16, 0, 0);                 \
        __builtin_amdgcn_global_load_lds((const u32*)(bsrc + koB_),           \
            (u32*)(&bbuf[(BI) * 8192 + tid * 16]), 16, 0, 0);                 \
    } while (0)

    STAGE(0, 0);
    STAGE(1, 1);

    int acur = 0, astg = 2;
    for (int s = 0; s < NS; ++s) {
        if (s + 1 < NS) asm volatile("s_waitcnt vmcnt(2)" ::: "memory");
        else            asm volatile("s_waitcnt vmcnt(0)" ::: "memory");
        __builtin_amdgcn_sched_barrier(0);
        __builtin_amdgcn_s_barrier();          // buf staged by ALL waves;
        __builtin_amdgcn_sched_barrier(0);     // prev-step reads all retired

        // frag reads: 8-elem (8 B) chunk kk = kc*4+l4 of a 64 B row, swizzled
        long long af[2][4], bf[2][2];
#pragma unroll
        for (int kc = 0; kc < 2; ++kc) {
            const int kk = kc * 4 + l4;
#pragma unroll
            for (int m = 0; m < 4; ++m) {
                int r = wr * 64 + m * 16 + l15;
                int g = (kk >> 1) ^ ((r >> 2) & 3);
                af[kc][m] = *(const long long*)(
                    &abuf[acur * 8192 + r * 64 + g * 16 + (kk & 1) * 8]);
            }
#pragma unroll
            for (int n = 0; n < 2; ++n) {
                int r = wc * 32 + n * 16 + l15;
                int g = (kk >> 1) ^ ((r >> 2) & 3);
                bf[kc][n] = *(const long long*)(
                    &bbuf[acur * 8192 + r * 64 + g * 16 + (kk & 1) * 8]);
            }
        }

        if (s + 2 < NS) STAGE(astg, s + 2);    // DMA flies under the MFMAs

        __builtin_amdgcn_s_setprio(1);
#pragma unroll
        for (int kc = 0; kc < 2; ++kc)
#pragma unroll
        for (int m = 0; m < 4; ++m)
#pragma unroll
        for (int n = 0; n < 2; ++n)
            acc[m][n] = __builtin_amdgcn_mfma_f32_16x16x32_fp8_fp8(
                af[kc][m], bf[kc][n], acc[m][n], 0, 0, 0);
        __builtin_amdgcn_s_setprio(0);

        acur = (acur == 2) ? 0 : acur + 1;
        astg = (astg == 2) ? 0 : astg + 1;
    }
#undef STAGE

    // ---- epilogue: partial logsumexp over this block's 128 cols ----
#pragma unroll
    for (int m = 0; m < 4; ++m) {
#pragma unroll
        for (int r = 0; r < 4; ++r) {
            const int lrow = wr * 64 + m * 16 + l4 * 4 + r;   // local row
            float lg[2];
            float mx = -1e30f;
#pragma unroll
            for (int n = 0; n < 2; ++n) {
                lg[n] = acc[m][n][r] * 5.0f;                  // /TEMP
                mx = fmaxf(mx, lg[n]);
            }
            mx = fmaxf(mx, __shfl_xor(mx, 1));
            mx = fmaxf(mx, __shfl_xor(mx, 2));
            mx = fmaxf(mx, __shfl_xor(mx, 4));
            mx = fmaxf(mx, __shfl_xor(mx, 8));
            float se = 0.f;
#pragma unroll
            for (int n = 0; n < 2; ++n) se += __expf(lg[n] - mx);
            se += __shfl_xor(se, 1);
            se += __shfl_xor(se, 2);
            se += __shfl_xor(se, 4);
            se += __shfl_xor(se, 8);
            if (l15 == 0) { sm_max[lrow][wc] = mx; sm_sum[lrow][wc] = se; }
            const int posc = (brow + lrow) & (NB - 1);        // global row % 512
#pragma unroll
            for (int n = 0; n < 2; ++n)
                if (bcol + wc * 32 + n * 16 + l15 == posc) sm_pos[lrow] = lg[n];
        }
    }
    __syncthreads();

    if (tid < BM) {
        const int lrow = tid;
        const int grow = brow + lrow;
        float gm = -1e30f;
#pragma unroll
        for (int c = 0; c < 4; ++c) gm = fmaxf(gm, sm_max[lrow][c]);
        float tot = 0.f;
#pragma unroll
        for (int c = 0; c < 4; ++c)
            tot += sm_sum[lrow][c] * __expf(sm_max[lrow][c] - gm);
        pmax_g[cb * NM + grow] = gm;
        psum_g[cb * NM + grow] = tot;
        if (((grow & (NB - 1)) >> 7) == cb) ppos_g[grow] = sm_pos[lrow];
    }
}

// ---------------------------------------------------------------------------
// Combine 4 col-block partials per row -> per-row loss term -> block partial.
__global__ __launch_bounds__(256) void reduce_kernel(
        const float* __restrict__ pmax_g, const float* __restrict__ psum_g,
        const float* __restrict__ ppos_g, float* __restrict__ part) {
    const int row = blockIdx.x * 256 + threadIdx.x;   // 32 blocks x 256
    float mxs[NCB];
    float gm = -1e30f;
#pragma unroll
    for (int c = 0; c < NCB; ++c) {
        mxs[c] = pmax_g[c * NM + row];
        gm = fmaxf(gm, mxs[c]);
    }
    float tot = 0.f;
#pragma unroll
    for (int c = 0; c < NCB; ++c)
        tot += psum_g[c * NM + row] * __expf(mxs[c] - gm);
    float term = gm + __logf(tot) - ppos_g[row];
#pragma unroll
    for (int off = 32; off > 0; off >>= 1) term += __shfl_xor(term, off);
    __shared__ float wsum[4];
    const int lane = threadIdx.x & 63, wv = threadIdx.x >> 6;
    if (lane == 0) wsum[wv] = term;
    __syncthreads();
    if (threadIdx.x == 0)
        part[blockIdx.x] = wsum[0] + wsum[1] + wsum[2] + wsum[3];
}

__global__ void finalize_kernel(const float* __restrict__ part,
                                float* __restrict__ out) {
    const int lane = threadIdx.x;                       // 64 threads
    float v = (lane < 32) ? part[lane] : 0.f;
#pragma unroll
    for (int off = 32; off > 0; off >>= 1) v += __shfl_xor(v, off);
    if (lane == 0) out[0] = v * (1.0f / (float)NM);
}

extern "C" void kernel_launch(void* const* d_in, const int* in_sizes, int n_in,
                              void* d_out, int out_size, void* d_ws, size_t ws_size,
                              hipStream_t stream) {
    const float* feat = (const float*)d_in[0];

    unsigned char* an = (unsigned char*)d_ws;              // 16 MB fp8
    unsigned char* zn = an + (size_t)NM * ND;              // 1 MB fp8
    float* pmax = (float*)(zn + (size_t)NB * ND);          // NCB*NM
    float* psum = pmax + NCB * NM;                         // NCB*NM
    float* ppos = psum + NCB * NM;                         // NM
    float* part = ppos + NM;                               // 32

    prep_kernel<<<NB, 512, 0, stream>>>(feat, an, zn);
    gemm_loss_kernel<<<(NM / BM) * NCB, 512, 0, stream>>>(an, zn, pmax, psum, ppos);
    reduce_kernel<<<NM / 256, 256, 0, stream>>>(pmax, psum, ppos, part);
    finalize_kernel<<<1, 64, 0, stream>>>(part, (float*)d_out);
}